// Round 10
// baseline (352.537 us; speedup 1.0000x reference)
//
#include <hip/hip_runtime.h>
#include <math.h>

constexpr int BB  = 32;
constexpr int SQL = 2048;
constexpr int SKL = 2048;
constexpr int DD  = 64;

using f32x4 = __attribute__((ext_vector_type(4))) float;
using bfrag = __attribute__((ext_vector_type(8))) short;   // 8 bf16 = 4 VGPR

static __device__ __forceinline__ unsigned short f2bf(float x) {
    unsigned u = __float_as_uint(x);
    u = u + 0x7FFFu + ((u >> 16) & 1u);          // round-nearest-even
    return (unsigned short)(u >> 16);
}
static __device__ __forceinline__ float bf2f(unsigned short h) {
    return __uint_as_float((unsigned)h << 16);
}

// async global->LDS, 16 B per lane (wave-uniform base + lane*16 dest;
// GLOBAL source address is per-lane -> source-side permutation is free)
static __device__ __forceinline__ void gld16(const void* g, void* l) {
    __builtin_amdgcn_global_load_lds(
        (const __attribute__((address_space(1))) void*)(size_t)g,
        (__attribute__((address_space(3))) void*)(unsigned)(size_t)l,
        16, 0, 0);
}

// ---- prepass: k fp32 -> swizzled bf16 hi/lo records (proven r6/r9).
// Per (b,c): 256 B = [hi 128B][lo 128B]; 16-B groups XOR'd by ((c&7)<<4).
__global__ __launch_bounds__(256) void split_k_swz(
    const float* __restrict__ k, unsigned char* __restrict__ kswz)
{
    const int i0 = blockIdx.x * blockDim.x + threadIdx.x;  // (b,c,g)
    const int g  = i0 & 7;
    const int c  = (i0 >> 3) & 2047;
    const int b  = i0 >> 14;
    const float* kp = k + ((size_t)(b * 2048 + c)) * DD + g * 8;
    bfrag h, lo;
    #pragma unroll
    for (int j = 0; j < 8; ++j) {
        const float x = kp[j];
        const unsigned short hh = f2bf(x);
        h[j]  = (short)hh;
        lo[j] = (short)f2bf(x - bf2f(hh));
    }
    const int sw = (c & 7) << 4;
    unsigned char* rec = kswz + ((size_t)(b * 2048 + c)) * 256;
    *(bfrag*)(rec + ((g * 16) ^ sw))       = h;
    *(bfrag*)(rec + 128 + ((g * 16) ^ sw)) = lo;
}

// ---- main: block = 8 waves = 16 q-rows x 2048 cols; wave w owns 256 cols.
// Both k (swizzled bf16 records) AND raw int32 mask are fed via per-wave LDS
// double buffers filled by global_load_lds DMA with counted vmcnt(5) — the
// 512 MB mask stream overlaps compute instead of running as a prepass.
template<bool PRE>
__global__ __launch_bounds__(512, 4) void sdpa_v10(
    const float* __restrict__ q, const float* __restrict__ k,
    const int* __restrict__ mask, const unsigned char* __restrict__ kswz,
    float* __restrict__ out)
{
    // per wave 10 KB: [k buf0 4K][k buf1 4K][m buf0 1K][m buf1 1K]
    __shared__ char pool[81920];

    const int t   = threadIdx.x;
    const int l   = t & 63;
    const int w   = t >> 6;
    const int lr  = l & 15;
    const int lg  = l >> 4;
    const int bid = blockIdx.x;
    const int swz = (bid & 7) * 512 + (bid >> 3);   // bijective XCD chunking
    const int b   = swz >> 7;                       // batch
    const int r0  = (swz & 127) * 16;               // q-row base
    const int c0  = w * 256;                        // wave's col base
    const size_t rowg = (size_t)b * SQL + (size_t)(r0 + lr);  // lane's q-row
    const int swk = (lr & 7) << 4;                  // k LDS swizzle key

    char* kseg = pool + w * 10240;
    char* mseg = kseg + 8192;

    // ---- q fragments (B operand), scale (log2e/8) folded, hi/lo split
    constexpr float QS = 0.18033688011112042f;      // 0.125 * log2(e)
    bfrag qh0, ql0, qh1, ql1;
    {
        const float* qp = q + rowg * DD + lg * 8;
        const f32x4 x0 = *reinterpret_cast<const f32x4*>(qp);
        const f32x4 x1 = *reinterpret_cast<const f32x4*>(qp + 4);
        const f32x4 y0 = *reinterpret_cast<const f32x4*>(qp + 32);
        const f32x4 y1 = *reinterpret_cast<const f32x4*>(qp + 36);
        #pragma unroll
        for (int j = 0; j < 4; ++j) {
            float a = x0[j] * QS, c = x1[j] * QS;
            float d = y0[j] * QS, e = y1[j] * QS;
            unsigned short h;
            h = f2bf(a); qh0[j]     = (short)h; ql0[j]     = (short)f2bf(a - bf2f(h));
            h = f2bf(c); qh0[j + 4] = (short)h; ql0[j + 4] = (short)f2bf(c - bf2f(h));
            h = f2bf(d); qh1[j]     = (short)h; ql1[j]     = (short)f2bf(d - bf2f(h));
            h = f2bf(e); qh1[j + 4] = (short)h; ql1[j + 4] = (short)f2bf(e - bf2f(h));
        }
    }

    const char* ksrc = PRE ? (const char*)(kswz + (size_t)b * SKL * 256) : nullptr;
    const float* kraw = PRE ? nullptr : k + (size_t)b * SKL * DD;

    // mask DMA: lane l fetches int4 for (row=l>>2, colgroup=(l&3)^((l>>3)&3));
    // the resulting LDS layout makes compute reads 2-way bank-aliased (free).
    const int* msrc = mask + ((size_t)b * SQL + (size_t)(r0 + (l >> 2))) * SKL
                           + c0 + (((l & 3) ^ ((l >> 3) & 3)) << 2);
    // compute-side LDS byte offset for this lane's mask int4 (constant)
    const int moff = lr * 64 + ((lg ^ ((lr >> 1) & 3)) << 4);
    // fallback: direct global mask pointer
    const int* mrp = PRE ? nullptr : mask + rowg * SKL + c0 + lg * 4;

#define STAGE(T)                                                               \
    do {                                                                       \
        char* _kd = kseg + (((T) & 1) << 12);                                  \
        if constexpr (PRE) {                                                   \
            const char* _ks = ksrc + (size_t)(c0 + (T) * 16) * 256;            \
            gld16(_ks + l * 16,        _kd + l * 16);                          \
            gld16(_ks + 1024 + l * 16, _kd + 1024 + l * 16);                   \
            gld16(_ks + 2048 + l * 16, _kd + 2048 + l * 16);                   \
            gld16(_ks + 3072 + l * 16, _kd + 3072 + l * 16);                   \
            gld16(msrc + (T) * 16, mseg + (((T) & 1) << 10) + l * 16);         \
        } else {                                                               \
            const float* _kc = kraw + (size_t)(c0 + (T) * 16 + lr) * DD;       \
            const f32x4 _a0 = *(const f32x4*)(_kc + lg * 8);                   \
            const f32x4 _a1 = *(const f32x4*)(_kc + lg * 8 + 4);               \
            const f32x4 _b0 = *(const f32x4*)(_kc + (lg + 4) * 8);             \
            const f32x4 _b1 = *(const f32x4*)(_kc + (lg + 4) * 8 + 4);         \
            bfrag _h, _o;                                                      \
            _Pragma("unroll")                                                  \
            for (int _j = 0; _j < 4; ++_j) {                                   \
                unsigned short _t;                                             \
                _t = f2bf(_a0[_j]); _h[_j]   = (short)_t;                      \
                _o[_j]   = (short)f2bf(_a0[_j] - bf2f(_t));                    \
                _t = f2bf(_a1[_j]); _h[_j+4] = (short)_t;                      \
                _o[_j+4] = (short)f2bf(_a1[_j] - bf2f(_t));                    \
            }                                                                  \
            char* _rec = _kd + lr * 256;                                       \
            *(bfrag*)(_rec + ((lg * 16) ^ swk))       = _h;                    \
            *(bfrag*)(_rec + 128 + ((lg * 16) ^ swk)) = _o;                    \
            _Pragma("unroll")                                                  \
            for (int _j = 0; _j < 4; ++_j) {                                   \
                unsigned short _t;                                             \
                _t = f2bf(_b0[_j]); _h[_j]   = (short)_t;                      \
                _o[_j]   = (short)f2bf(_b0[_j] - bf2f(_t));                    \
                _t = f2bf(_b1[_j]); _h[_j+4] = (short)_t;                      \
                _o[_j+4] = (short)f2bf(_b1[_j] - bf2f(_t));                    \
            }                                                                  \
            *(bfrag*)(_rec + (((lg + 4) * 16) ^ swk))       = _h;              \
            *(bfrag*)(_rec + 128 + (((lg + 4) * 16) ^ swk)) = _o;              \
        }                                                                      \
    } while (0)

#define ITER(T, VMC)                                                           \
    do {                                                                       \
        if constexpr (PRE)                                                     \
            asm volatile("s_waitcnt vmcnt(" #VMC ")" ::: "memory");            \
        const char* _c = kseg + (((T) & 1) << 12) + lr * 256;                  \
        const bfrag _kh0 = *(const bfrag*)(_c + ((lg * 16) ^ swk));            \
        const bfrag _kh1 = *(const bfrag*)(_c + (((lg + 4) * 16) ^ swk));      \
        const bfrag _kl0 = *(const bfrag*)(_c + 128 + ((lg * 16) ^ swk));      \
        const bfrag _kl1 = *(const bfrag*)(_c + 128 + (((lg + 4) * 16) ^ swk));\
        int4 _mv;                                                              \
        if constexpr (PRE)                                                     \
            _mv = *(const int4*)(mseg + (((T) & 1) << 10) + moff);             \
        else                                                                   \
            _mv = *(const int4*)(mrp + (T) * 16);                              \
        asm volatile("s_waitcnt lgkmcnt(0)" ::: "memory");                     \
        __builtin_amdgcn_sched_barrier(0);                                     \
        if constexpr ((T) + 2 < 16) STAGE((T) + 2);                            \
        f32x4 _a1 = {0.f, 0.f, 0.f, 0.f};                                      \
        f32x4 _a2 = {0.f, 0.f, 0.f, 0.f};                                      \
        f32x4 _a3 = {0.f, 0.f, 0.f, 0.f};                                      \
        _a1 = __builtin_amdgcn_mfma_f32_16x16x32_bf16(_kl0, qh0, _a1, 0, 0, 0);\
        _a2 = __builtin_amdgcn_mfma_f32_16x16x32_bf16(_kh0, ql0, _a2, 0, 0, 0);\
        _a3 = __builtin_amdgcn_mfma_f32_16x16x32_bf16(_kh0, qh0, _a3, 0, 0, 0);\
        _a1 = __builtin_amdgcn_mfma_f32_16x16x32_bf16(_kl1, qh1, _a1, 0, 0, 0);\
        _a2 = __builtin_amdgcn_mfma_f32_16x16x32_bf16(_kh1, ql1, _a2, 0, 0, 0);\
        _a3 = __builtin_amdgcn_mfma_f32_16x16x32_bf16(_kh1, qh1, _a3, 0, 0, 0);\
        const f32x4 _s = (_a1 + _a2) + _a3;                                    \
        const float _e0 = (_mv.x != 0) ? exp2f(_s[0]) : 0.f;                   \
        const float _e1 = (_mv.y != 0) ? exp2f(_s[1]) : 0.f;                   \
        const float _e2 = (_mv.z != 0) ? exp2f(_s[2]) : 0.f;                   \
        const float _e3 = (_mv.w != 0) ? exp2f(_s[3]) : 0.f;                   \
        psum += (_e0 + _e1) + (_e2 + _e3);                                     \
        sc[2 * (T)    ] = (unsigned)f2bf(_e0) | ((unsigned)f2bf(_e1) << 16);   \
        sc[2 * (T) + 1] = (unsigned)f2bf(_e2) | ((unsigned)f2bf(_e3) << 16);   \
    } while (0)

    unsigned sc[32];                  // packed bf16 exp values (32 VGPR)
    float psum = 0.f;

    STAGE(0);
    STAGE(1);

    ITER(0,  5); ITER(1,  5); ITER(2,  5); ITER(3,  5);
    ITER(4,  5); ITER(5,  5); ITER(6,  5); ITER(7,  5);
    ITER(8,  5); ITER(9,  5); ITER(10, 5); ITER(11, 5);
    ITER(12, 5); ITER(13, 5); ITER(14, 5); ITER(15, 0);
#undef ITER
#undef STAGE

    // ---- row sums: lanes {l, l^16, l^32, l^48} share a q-row
    float s = psum;
    s += __shfl_xor(s, 16, 64);
    s += __shfl_xor(s, 32, 64);

    __syncthreads();                  // all LDS traffic done; pool reusable
    float* s_red = (float*)pool;      // aliased scratch (512 B)
    if (l < 16) s_red[w * 16 + lr] = s;
    __syncthreads();

    float tot = 0.f;
    #pragma unroll
    for (int ww = 0; ww < 8; ++ww)
        tot += s_red[ww * 16 + lr];
    const float rinv = 1.0f / tot;

    // ---- unpack, normalize, float4 store
    float* op = out + rowg * SKL + c0 + lg * 4;
    #pragma unroll
    for (int T = 0; T < 16; ++T) {
        const unsigned p01 = sc[2 * T];
        const unsigned p23 = sc[2 * T + 1];
        f32x4 o;
        o[0] = bf2f((unsigned short)(p01 & 0xffffu)) * rinv;
        o[1] = bf2f((unsigned short)(p01 >> 16))     * rinv;
        o[2] = bf2f((unsigned short)(p23 & 0xffffu)) * rinv;
        o[3] = bf2f((unsigned short)(p23 >> 16))     * rinv;
        *reinterpret_cast<f32x4*>(op + T * 16) = o;
    }
}

extern "C" void kernel_launch(void* const* d_in, const int* in_sizes, int n_in,
                              void* d_out, int out_size, void* d_ws, size_t ws_size,
                              hipStream_t stream) {
    const float* q    = (const float*)d_in[0];
    const float* k    = (const float*)d_in[1];
    const int*   mask = (const int*)d_in[2];
    float*       out  = (float*)d_out;

    const size_t KS_B = (size_t)BB * SKL * 256;   // 16.78 MB swizzled k

    dim3 grid(4096);    // XCD-swizzled in-kernel; 8 waves each

    if (ws_size >= KS_B) {
        unsigned char* ksp = (unsigned char*)d_ws;
        split_k_swz<<<2048, 256, 0, stream>>>(k, ksp);
        sdpa_v10<true><<<grid, 512, 0, stream>>>(q, k, mask, ksp, out);
    } else {
        sdpa_v10<false><<<grid, 512, 0, stream>>>(q, k, mask, nullptr, out);
    }
}